// Round 3
// baseline (441.832 us; speedup 1.0000x reference)
//
#include <hip/hip_runtime.h>

// Hierarchy: B0=8, B1=16, B2=16; BATCH=32768.
// out[b, (a0*16+a1)*16 + a2] =
//   cumprod(dc0[b])[a0] * cumprod_grp16(dc1[b])[a0,a1] * cumprod_grp16(dc2[b])[a0*16+a1, a2]
//
// Wave-autonomous: wave w owns a0 = w (16 groups x 4 lanes). No LDS/barriers.
// Each block handles TWO rows; both dc2 float4 loads issued first so two
// VMEM loads are in flight per thread (MLP), prefix math fills the latency.

#define NB0 8
#define NB1 16
#define NB2 16
#define GROUPS (NB0 * NB1)      // 128 groups of 16 leaves
#define ROW_LEN (GROUPS * NB2)  // 2048

__global__ __launch_bounds__(512)
void det_prob_kernel(const float* __restrict__ dc0,
                     const float* __restrict__ dc1,
                     const float* __restrict__ dc2,
                     float* __restrict__ out)
{
    const int t    = threadIdx.x;
    const int row0 = blockIdx.x * 2;
    const int row1 = row0 + 1;

    const size_t off2A = (size_t)row0 * ROW_LEN;
    const size_t off2B = (size_t)row1 * ROW_LEN;

    // ---- Issue both big loads FIRST (two outstanding dwordx4 per thread) ----
    const float4 xA = reinterpret_cast<const float4*>(dc2 + off2A)[t];
    const float4 xB = reinterpret_cast<const float4*>(dc2 + off2B)[t];

    const int wave = t >> 6;   // == a0 for this wave
    const int lane = t & 63;
    const int j    = lane & 3;

    // ---- dc1 values (4-way broadcast within wave), both rows ----
    const size_t g1 = (size_t)wave * NB1 + (size_t)(lane >> 2);
    const float d1A = dc1[(size_t)row0 * GROUPS + g1];
    const float d1B = dc1[(size_t)row1 * GROUPS + g1];

    // ---- c0 = cumprod(dc0[row])[a0]; block-uniform addr -> scalar loads ----
    float c0A = 1.0f, c0B = 1.0f;
    #pragma unroll
    for (int k = 0; k < NB0; ++k) {
        const float vA = dc0[(size_t)row0 * NB0 + k];
        const float vB = dc0[(size_t)row1 * NB0 + k];
        if (k <= wave) { c0A *= vA; c0B *= vB; }
    }

    // ---- inclusive group scan of dc1 via quad-stride lane scan, both rows ----
    float sA = d1A, sB = d1B;
    #pragma unroll
    for (int off = 4; off <= 32; off <<= 1) {
        const float uA = __shfl_up(sA, off, 64);
        const float uB = __shfl_up(sB, off, 64);
        if (lane >= off) { sA *= uA; sB *= uB; }
    }
    const float prefixA = c0A * sA;
    const float prefixB = c0B * sB;

    // ---- local cumprod of 4 dc2 elements, row A ----
    float a0v = xA.x;
    float a1v = a0v * xA.y;
    float a2v = a1v * xA.z;
    float a3v = a2v * xA.w;
    // row B
    float b0v = xB.x;
    float b1v = b0v * xB.y;
    float b2v = b1v * xB.z;
    float b3v = b2v * xB.w;

    // ---- quad-level exclusive prefix of per-lane totals, both rows ----
    const int qbase = lane & ~3;
    const float tA0 = __shfl(a3v, qbase + 0, 64);
    const float tA1 = __shfl(a3v, qbase + 1, 64);
    const float tA2 = __shfl(a3v, qbase + 2, 64);
    const float tB0 = __shfl(b3v, qbase + 0, 64);
    const float tB1 = __shfl(b3v, qbase + 1, 64);
    const float tB2 = __shfl(b3v, qbase + 2, 64);

    float pA = prefixA, pB = prefixB;
    if (j > 0) { pA *= tA0; pB *= tB0; }
    if (j > 1) { pA *= tA1; pB *= tB1; }
    if (j > 2) { pA *= tA2; pB *= tB2; }

    float4 oA, oB;
    oA.x = a0v * pA; oA.y = a1v * pA; oA.z = a2v * pA; oA.w = a3v * pA;
    oB.x = b0v * pB; oB.y = b1v * pB; oB.z = b2v * pB; oB.w = b3v * pB;
    reinterpret_cast<float4*>(out + off2A)[t] = oA;
    reinterpret_cast<float4*>(out + off2B)[t] = oB;
}

extern "C" void kernel_launch(void* const* d_in, const int* in_sizes, int n_in,
                              void* d_out, int out_size, void* d_ws, size_t ws_size,
                              hipStream_t stream) {
    const float* dc0 = (const float*)d_in[0];
    const float* dc1 = (const float*)d_in[1];
    const float* dc2 = (const float*)d_in[2];
    float* out = (float*)d_out;

    const int batch = in_sizes[0] / NB0;  // 32768
    det_prob_kernel<<<batch / 2, 512, 0, stream>>>(dc0, dc1, dc2, out);
}